// Round 24
// baseline (19490.146 us; speedup 1.0000x reference)
//
#include <hip/hip_runtime.h>

#define LOG2E 1.44269504088896340736f

__device__ __forceinline__ float lrelu(float z) { return fmaxf(z, 0.01f * z); }
__device__ __forceinline__ float sigf(float z) {
    float p = __builtin_amdgcn_exp2f(-LOG2E * z);
    return __builtin_amdgcn_rcpf(1.0f + p);
}

#define WQ(i) __int_as_float(__builtin_amdgcn_readlane(__float_as_int(wreg[(i) >> 6]), (i) & 63))

// =================== Phase 1: recurrent h-path (R11 + VGPR-pinned) ==========
// R23 finding: readlane ~8-16 cyc/float, LDS 3 cyc/float on a 90%-utilized
// shared pipe, SMEM unstreamable. The free mechanism: wave-uniform weights
// RESIDENT IN VGPRS cost zero per step (plain FMA operand). At 1 wave/SIMD
// ~450 VGPRs usable; working set ~105. Pin 320 weights (Wh2 rows 18..33)
// via asm "+v" (prevents re-sinking of the uniform loads into the loop).
// Split: LDS = Wh2 rows 0..17 (360, R11's low-util knee); VGPR = 320;
// RL = 532: 0..99 Wh1 | 100..149 bh1 | 150..469 Wh2 rows 34..49
//           | 470..489 bh2 | 490..529 Wh3 | 530..531 bh3
__global__ void __launch_bounds__(256, 1)
hpath_kernel(const float* __restrict__ w,
             const float* __restrict__ Wh1, const float* __restrict__ bh1,
             const float* __restrict__ Wh2, const float* __restrict__ bh2,
             const float* __restrict__ Wh3, const float* __restrict__ bh3,
             float2* __restrict__ out, int B, int T)
{
    __shared__ float4 sW2[90];   // Wh2 rows 0..17
    {
        float* s2 = (float*)sW2;
        for (int i = threadIdx.x; i < 360; i += 256) s2[i] = Wh2[i];
    }

    const int lane = threadIdx.x & 63;
    float wreg[9];
#pragma unroll
    for (int r = 0; r < 9; ++r) {
        const int idx = r * 64 + lane;
        float v = 0.f;
        if      (idx < 100) v = Wh1[idx];
        else if (idx < 150) v = bh1[idx - 100];
        else if (idx < 470) v = Wh2[680 + (idx - 150)];   // rows 34..49
        else if (idx < 490) v = bh2[idx - 470];
        else if (idx < 530) v = Wh3[idx - 490];
        else if (idx < 532) v = bh3[idx - 530];
        wreg[r] = v;
    }

    // VGPR-pinned weights: Wh2 rows 18..33 (320 floats), uniform loads,
    // forced into VGPRs so they stay resident across the whole t-loop.
    float wv[320];
#pragma unroll
    for (int i = 0; i < 320; ++i) {
        wv[i] = Wh2[360 + i];
        asm volatile("" : "+v"(wv[i]));
    }
    __syncthreads();

    const int bidx = blockIdx.x * blockDim.x + threadIdx.x;
    if (bidx >= B) return;   // B % 256 == 0: never taken

    float h0 = w[2 * bidx], h1 = w[2 * bidx + 1];
    float2* __restrict__ orow = out + (size_t)bidx * (size_t)T;

    for (int t = 0; t < T; ++t) {
        // ---- 2 -> 50, lrelu (RL) ----
        float a1[50];
#pragma unroll
        for (int j = 0; j < 50; ++j)
            a1[j] = lrelu(fmaf(h0, WQ(j), fmaf(h1, WQ(50 + j), WQ(100 + j))));

        // ---- 50 -> 20 accumulate ----
        float acc[20];
#pragma unroll
        for (int c = 0; c < 20; ++c) acc[c] = WQ(470 + c);

#pragma unroll
        for (int k = 0; k < 18; ++k) {          // rows 0..17 via LDS
            const float ak = a1[k];
#pragma unroll
            for (int c = 0; c < 5; ++c) {
                const float4 v = sW2[k * 5 + c];
                acc[4*c+0] = fmaf(ak, v.x, acc[4*c+0]);
                acc[4*c+1] = fmaf(ak, v.y, acc[4*c+1]);
                acc[4*c+2] = fmaf(ak, v.z, acc[4*c+2]);
                acc[4*c+3] = fmaf(ak, v.w, acc[4*c+3]);
            }
        }
#pragma unroll
        for (int k = 18; k < 34; ++k) {         // rows 18..33 via VGPR (free)
            const float ak = a1[k];
#pragma unroll
            for (int c = 0; c < 20; ++c)
                acc[c] = fmaf(ak, wv[(k - 18) * 20 + c], acc[c]);
        }
#pragma unroll
        for (int k = 34; k < 50; ++k) {         // rows 34..49 via RL
            const float ak = a1[k];
#pragma unroll
            for (int c = 0; c < 20; ++c)
                acc[c] = fmaf(ak, WQ(150 + (k - 34) * 20 + c), acc[c]);
        }

        // ---- 20 -> 2, lrelu ----
        float z0 = WQ(530), z1 = WQ(531);
#pragma unroll
        for (int k = 0; k < 20; ++k) {
            const float a2k = lrelu(acc[k]);
            z0 = fmaf(a2k, WQ(490 + 2 * k + 0), z0);
            z1 = fmaf(a2k, WQ(491 + 2 * k), z1);
        }
        h0 = lrelu(z0); h1 = lrelu(z1);
        orow[t] = make_float2(h0, h1);
    }
}

// =================== Phase 2: x = G(h), 4 pt/thread + VGPR-pinned ===========
// R6 body (2.06ms). Pin Wx2 rows 40..49 (200 floats) in VGPRs -> LDS reads
// 310 -> ~265/iter. No launch_bounds cap (R17/R18: caps spill, spill > gain).
__global__ void xpath_kernel(const float* __restrict__ Wx1, const float* __restrict__ bx1,
                             const float* __restrict__ Wx2, const float* __restrict__ bx2,
                             const float* __restrict__ Wx3, const float* __restrict__ bx3,
                             float2* __restrict__ out, int NG)
{
    __shared__ float4 sL1[50];   // (W1[0][k], W1[1][k], b1[k], 0)
    __shared__ float4 sW2[200];  // Wx2 rows 0..39
    __shared__ float4 sW3[10];
    __shared__ float4 sB2[5];
    __shared__ float2 sB3;
    {
        const int tid = threadIdx.x;
        if (tid < 50) sL1[tid] = make_float4(Wx1[tid], Wx1[50 + tid], bx1[tid], 0.f);
        float* s2 = (float*)sW2;
        for (int i = tid; i < 800; i += 256) s2[i] = Wx2[i];
        if (tid < 40) ((float*)sW3)[tid] = Wx3[tid];
        if (tid < 20) ((float*)sB2)[tid] = bx2[tid];
        if (tid == 0) sB3 = make_float2(bx3[0], bx3[1]);
    }

    // VGPR-pinned: Wx2 rows 40..49 (200 floats)
    float wvx[200];
#pragma unroll
    for (int i = 0; i < 200; ++i) {
        wvx[i] = Wx2[800 + i];
        asm volatile("" : "+v"(wvx[i]));
    }
    __syncthreads();

    const int stride = gridDim.x * blockDim.x;
    for (int g = blockIdx.x * blockDim.x + threadIdx.x; g < NG; g += stride) {
        const float4 hv01 = reinterpret_cast<const float4*>(out)[2 * g];
        const float4 hv23 = reinterpret_cast<const float4*>(out)[2 * g + 1];
        const float h0[4] = {hv01.x, hv01.z, hv23.x, hv23.z};
        const float h1[4] = {hv01.y, hv01.w, hv23.y, hv23.w};

        float acc[4][20];
#pragma unroll
        for (int c4 = 0; c4 < 5; ++c4) {
            const float4 b = sB2[c4];
#pragma unroll
            for (int p = 0; p < 4; ++p) {
                acc[p][4 * c4 + 0] = b.x; acc[p][4 * c4 + 1] = b.y;
                acc[p][4 * c4 + 2] = b.z; acc[p][4 * c4 + 3] = b.w;
            }
        }
#pragma unroll
        for (int k = 0; k < 50; ++k) {
            const float4 l1 = sL1[k];
            float xk[4];
#pragma unroll
            for (int p = 0; p < 4; ++p)
                xk[p] = sigf(fmaf(h0[p], l1.x, fmaf(h1[p], l1.y, l1.z)));
            if (k < 40) {                        // rows 0..39 via LDS
#pragma unroll
                for (int c4 = 0; c4 < 5; ++c4) {
                    const float4 v = sW2[k * 5 + c4];
#pragma unroll
                    for (int p = 0; p < 4; ++p) {
                        acc[p][4 * c4 + 0] = fmaf(xk[p], v.x, acc[p][4 * c4 + 0]);
                        acc[p][4 * c4 + 1] = fmaf(xk[p], v.y, acc[p][4 * c4 + 1]);
                        acc[p][4 * c4 + 2] = fmaf(xk[p], v.z, acc[p][4 * c4 + 2]);
                        acc[p][4 * c4 + 3] = fmaf(xk[p], v.w, acc[p][4 * c4 + 3]);
                    }
                }
            } else {                             // rows 40..49 via VGPR (free)
#pragma unroll
                for (int c = 0; c < 20; ++c) {
                    const float wvv = wvx[(k - 40) * 20 + c];
#pragma unroll
                    for (int p = 0; p < 4; ++p)
                        acc[p][c] = fmaf(xk[p], wvv, acc[p][c]);
                }
            }
        }
        const float2 b3 = sB3;
        float z0[4], z1[4];
#pragma unroll
        for (int p = 0; p < 4; ++p) { z0[p] = b3.x; z1[p] = b3.y; }
#pragma unroll
        for (int q = 0; q < 10; ++q) {
            const float4 v = sW3[q];
#pragma unroll
            for (int p = 0; p < 4; ++p) {
                const float x2a = sigf(acc[p][2 * q + 0]);
                const float x2b = sigf(acc[p][2 * q + 1]);
                z0[p] = fmaf(x2a, v.x, z0[p]); z1[p] = fmaf(x2a, v.y, z1[p]);
                z0[p] = fmaf(x2b, v.z, z0[p]); z1[p] = fmaf(x2b, v.w, z1[p]);
            }
        }
        const float4 o01 = make_float4(sigf(z0[0]), sigf(z1[0]), sigf(z0[1]), sigf(z1[1]));
        const float4 o23 = make_float4(sigf(z0[2]), sigf(z1[2]), sigf(z0[3]), sigf(z1[3]));
        reinterpret_cast<float4*>(out)[2 * g]     = o01;
        reinterpret_cast<float4*>(out)[2 * g + 1] = o23;
    }
}

extern "C" void kernel_launch(void* const* d_in, const int* in_sizes, int n_in,
                              void* d_out, int out_size, void* d_ws, size_t ws_size,
                              hipStream_t stream)
{
    const float* w   = (const float*)d_in[0];
    const float* Wh1 = (const float*)d_in[1];
    const float* bh1 = (const float*)d_in[2];
    const float* Wh2 = (const float*)d_in[3];
    const float* bh2 = (const float*)d_in[4];
    const float* Wh3 = (const float*)d_in[5];
    const float* bh3 = (const float*)d_in[6];
    const float* Wx1 = (const float*)d_in[7];
    const float* bx1 = (const float*)d_in[8];
    const float* Wx2 = (const float*)d_in[9];
    const float* bx2 = (const float*)d_in[10];
    const float* Wx3 = (const float*)d_in[11];
    const float* bx3 = (const float*)d_in[12];

    const int B  = in_sizes[0] / 2;        // 65536
    const int T  = out_size / (B * 2);     // 512
    const int NP = B * T;
    const int NG = NP / 4;

    float2* out2 = (float2*)d_out;

    hpath_kernel<<<(B + 255) / 256, 256, 0, stream>>>(
        w, Wh1, bh1, Wh2, bh2, Wh3, bh3, out2, B, T);

    xpath_kernel<<<4096, 256, 0, stream>>>(
        Wx1, bx1, Wx2, bx2, Wx3, bx3, out2, NG);
}

// Round 25
// 3554.684 us; speedup vs baseline: 5.4829x; 5.4829x over previous
//
#include <hip/hip_runtime.h>

#define LOG2E 1.44269504088896340736f

__device__ __forceinline__ float lrelu(float z) { return fmaxf(z, 0.01f * z); }
__device__ __forceinline__ float sigf(float z) {
    float p = __builtin_amdgcn_exp2f(-LOG2E * z);
    return __builtin_amdgcn_rcpf(1.0f + p);
}

#define WQ(i) __int_as_float(__builtin_amdgcn_readlane(__float_as_int(wreg[(i) >> 6]), (i) & 63))

// ====== PC-v5: pc4 structure, SGB/pb stripped, VGPR-pin 140/wave + X-trip LDS
// R24: 320-float pin overflowed the 256-VGPR cap (FETCH 12GB scratch). PC
// working set is only ~48-100 VGPR (R19/R21/R23) -> 140-float pin fits.
// R23: VALU-busy 13.9K/step, RL ~8cyc/float is the critical path; LDS pipe
// only 46% util. So: (1) pin 140 floats/wave in VGPRs (free per step);
// (2) move X's Wx1-trip (150 RL, 3-chained per k) to an LDS f4 table.
//   F wreg(332): 0..99 Wh1 | 100..149 bh1 | 150..269 Wh2 rows 44..49
//                | 270..289 bh2 | 290..329 Wh3 | 330..331 bh3
//   F pin(140):  Wh2 rows 37..43   F LDS: Wh2 rows 0..36 (185 f4)
//   X wreg(142): 0..79 Wx2 rows 46..49 | 80..99 bx2 | 100..139 Wx3 | 140..141 bx3
//   X pin(140):  Wx2 rows 39..45   X LDS: Wx2 rows 0..38 (195 f4) + Wx1-trip (50 f4)
__global__ void __launch_bounds__(256, 1)
pc5_kernel(const float* __restrict__ w,
           const float* __restrict__ Wh1, const float* __restrict__ bh1,
           const float* __restrict__ Wh2, const float* __restrict__ bh2,
           const float* __restrict__ Wh3, const float* __restrict__ bh3,
           const float* __restrict__ Wx1, const float* __restrict__ bx1,
           const float* __restrict__ Wx2, const float* __restrict__ bx2,
           const float* __restrict__ Wx3, const float* __restrict__ bx3,
           float2* __restrict__ out, int B, int T)
{
    __shared__ float4 sW2h[185];       // Wh2 rows 0..36
    __shared__ float4 sW2x[195];       // Wx2 rows 0..38
    __shared__ float4 sL1x[50];        // (Wx1[0][k], Wx1[1][k], bx1[k], 0)
    __shared__ float2 hbuf[2][256];    // double-buffered h handoff

    {
        float* a = (float*)sW2h;
        for (int i = threadIdx.x; i < 740; i += 256) a[i] = Wh2[i];
        float* b = (float*)sW2x;
        for (int i = threadIdx.x; i < 780; i += 256) b[i] = Wx2[i];
        if (threadIdx.x < 50)
            sL1x[threadIdx.x] = make_float4(Wx1[threadIdx.x], Wx1[50 + threadIdx.x],
                                            bx1[threadIdx.x], 0.f);
    }

    const int wid  = threadIdx.x >> 6;     // 0..3
    const int lane = threadIdx.x & 63;
    const bool is_f = (wid < 2);

    float wreg[6];
    float wv[140];
    if (is_f) {
#pragma unroll
        for (int r = 0; r < 6; ++r) {
            const int idx = r * 64 + lane;
            float v = 0.f;
            if      (idx < 100) v = Wh1[idx];
            else if (idx < 150) v = bh1[idx - 100];
            else if (idx < 270) v = Wh2[880 + (idx - 150)];   // rows 44..49
            else if (idx < 290) v = bh2[idx - 270];
            else if (idx < 330) v = Wh3[idx - 290];
            else if (idx < 332) v = bh3[idx - 330];
            wreg[r] = v;
        }
#pragma unroll
        for (int i = 0; i < 140; ++i) {        // pin Wh2 rows 37..43
            wv[i] = Wh2[740 + i];
            asm volatile("" : "+v"(wv[i]));
        }
    } else {
#pragma unroll
        for (int r = 0; r < 6; ++r) {
            const int idx = r * 64 + lane;
            float v = 0.f;
            if      (idx < 80)  v = Wx2[920 + idx];           // rows 46..49
            else if (idx < 100) v = bx2[idx - 80];
            else if (idx < 140) v = Wx3[idx - 100];
            else if (idx < 142) v = bx3[idx - 140];
            wreg[r] = v;
        }
#pragma unroll
        for (int i = 0; i < 140; ++i) {        // pin Wx2 rows 39..45
            wv[i] = Wx2[780 + i];
            asm volatile("" : "+v"(wv[i]));
        }
    }
    __syncthreads();

    const int lw = is_f ? wid : (wid - 2);
    const int lpA = lw * 128 + lane;
    const int lpB = lpA + 64;
    const int pA  = blockIdx.x * 256 + lpA;
    const int pB  = blockIdx.x * 256 + lpB;

    float hA0 = 0.f, hA1 = 0.f, hB0 = 0.f, hB1 = 0.f;
    if (is_f) {
        hA0 = w[2 * pA]; hA1 = w[2 * pA + 1];
        hB0 = w[2 * pB]; hB1 = w[2 * pB + 1];
    }
    float2* __restrict__ orowA = out + (size_t)pA * (size_t)T;
    float2* __restrict__ orowB = out + (size_t)pB * (size_t)T;

    for (int t = 0; t <= T; ++t) {
        if (is_f) {
            if (t < T) {
                // ===== F: h = lrelu3(h), 2 points, broadcasts shared =====
                float a1A[50], a1B[50];
#pragma unroll
                for (int j = 0; j < 50; ++j) {
                    const float s0 = WQ(j), s1 = WQ(50 + j), sb = WQ(100 + j);
                    a1A[j] = lrelu(fmaf(hA0, s0, fmaf(hA1, s1, sb)));
                    a1B[j] = lrelu(fmaf(hB0, s0, fmaf(hB1, s1, sb)));
                }
                float accA[20], accB[20];
#pragma unroll
                for (int c = 0; c < 20; ++c) {
                    const float bv = WQ(270 + c);
                    accA[c] = bv; accB[c] = bv;
                }
#pragma unroll
                for (int k = 0; k < 37; ++k) {          // rows 0..36 via LDS
                    const float akA = a1A[k], akB = a1B[k];
#pragma unroll
                    for (int c = 0; c < 5; ++c) {
                        const float4 v = sW2h[k * 5 + c];
                        accA[4*c+0] = fmaf(akA, v.x, accA[4*c+0]);
                        accA[4*c+1] = fmaf(akA, v.y, accA[4*c+1]);
                        accA[4*c+2] = fmaf(akA, v.z, accA[4*c+2]);
                        accA[4*c+3] = fmaf(akA, v.w, accA[4*c+3]);
                        accB[4*c+0] = fmaf(akB, v.x, accB[4*c+0]);
                        accB[4*c+1] = fmaf(akB, v.y, accB[4*c+1]);
                        accB[4*c+2] = fmaf(akB, v.z, accB[4*c+2]);
                        accB[4*c+3] = fmaf(akB, v.w, accB[4*c+3]);
                    }
                }
#pragma unroll
                for (int k = 37; k < 44; ++k) {         // rows 37..43 via pin (free)
                    const float akA = a1A[k], akB = a1B[k];
#pragma unroll
                    for (int c = 0; c < 20; ++c) {
                        const float wvv = wv[(k - 37) * 20 + c];
                        accA[c] = fmaf(akA, wvv, accA[c]);
                        accB[c] = fmaf(akB, wvv, accB[c]);
                    }
                }
#pragma unroll
                for (int k = 44; k < 50; ++k) {         // rows 44..49 via RL
                    const float akA = a1A[k], akB = a1B[k];
#pragma unroll
                    for (int c = 0; c < 20; ++c) {
                        const float wvv = WQ(150 + (k - 44) * 20 + c);
                        accA[c] = fmaf(akA, wvv, accA[c]);
                        accB[c] = fmaf(akB, wvv, accB[c]);
                    }
                }
                float zA0 = WQ(330), zA1 = WQ(331);
                float zB0 = zA0, zB1 = zA1;
#pragma unroll
                for (int k = 0; k < 20; ++k) {
                    const float wx = WQ(290 + 2 * k), wy = WQ(291 + 2 * k);
                    const float eA = lrelu(accA[k]), eB = lrelu(accB[k]);
                    zA0 = fmaf(eA, wx, zA0); zA1 = fmaf(eA, wy, zA1);
                    zB0 = fmaf(eB, wx, zB0); zB1 = fmaf(eB, wy, zB1);
                }
                hA0 = lrelu(zA0); hA1 = lrelu(zA1);
                hB0 = lrelu(zB0); hB1 = lrelu(zB1);

                hbuf[t & 1][lpA] = make_float2(hA0, hA1);
                hbuf[t & 1][lpB] = make_float2(hB0, hB1);
            }
        } else {
            if (t > 0) {
                // ===== X: x_s = sig3(h_s), s = t-1, 2 points =====
                const int s = t - 1;
                const float2 hvA = hbuf[s & 1][lpA];
                const float2 hvB = hbuf[s & 1][lpB];

                float accA[20], accB[20];
#pragma unroll
                for (int c = 0; c < 20; ++c) {
                    const float bv = WQ(80 + c);
                    accA[c] = bv; accB[c] = bv;
                }
#pragma unroll
                for (int k = 0; k < 50; ++k) {
                    const float4 l1 = sL1x[k];           // Wx1-trip via LDS
                    const float xkA = sigf(fmaf(hvA.x, l1.x, fmaf(hvA.y, l1.y, l1.z)));
                    const float xkB = sigf(fmaf(hvB.x, l1.x, fmaf(hvB.y, l1.y, l1.z)));
                    if (k < 39) {                        // rows 0..38 via LDS
#pragma unroll
                        for (int c = 0; c < 5; ++c) {
                            const float4 v = sW2x[k * 5 + c];
                            accA[4*c+0] = fmaf(xkA, v.x, accA[4*c+0]);
                            accA[4*c+1] = fmaf(xkA, v.y, accA[4*c+1]);
                            accA[4*c+2] = fmaf(xkA, v.z, accA[4*c+2]);
                            accA[4*c+3] = fmaf(xkA, v.w, accA[4*c+3]);
                            accB[4*c+0] = fmaf(xkB, v.x, accB[4*c+0]);
                            accB[4*c+1] = fmaf(xkB, v.y, accB[4*c+1]);
                            accB[4*c+2] = fmaf(xkB, v.z, accB[4*c+2]);
                            accB[4*c+3] = fmaf(xkB, v.w, accB[4*c+3]);
                        }
                    } else if (k < 46) {                 // rows 39..45 via pin (free)
#pragma unroll
                        for (int c = 0; c < 20; ++c) {
                            const float wvv = wv[(k - 39) * 20 + c];
                            accA[c] = fmaf(xkA, wvv, accA[c]);
                            accB[c] = fmaf(xkB, wvv, accB[c]);
                        }
                    } else {                             // rows 46..49 via RL
#pragma unroll
                        for (int c = 0; c < 20; ++c) {
                            const float wvv = WQ((k - 46) * 20 + c);
                            accA[c] = fmaf(xkA, wvv, accA[c]);
                            accB[c] = fmaf(xkB, wvv, accB[c]);
                        }
                    }
                }
                float zA0 = WQ(140), zA1 = WQ(141);
                float zB0 = zA0, zB1 = zA1;
#pragma unroll
                for (int k = 0; k < 20; ++k) {
                    const float wx = WQ(100 + 2 * k), wy = WQ(101 + 2 * k);
                    const float eA = sigf(accA[k]), eB = sigf(accB[k]);
                    zA0 = fmaf(eA, wx, zA0); zA1 = fmaf(eA, wy, zA1);
                    zB0 = fmaf(eB, wx, zB0); zB1 = fmaf(eB, wy, zB1);
                }
                orowA[s] = make_float2(sigf(zA0), sigf(zA1));
                orowB[s] = make_float2(sigf(zB0), sigf(zB1));
            }
        }
        __syncthreads();   // orders hbuf write (iter t) -> read (iter t+1)
    }
}

extern "C" void kernel_launch(void* const* d_in, const int* in_sizes, int n_in,
                              void* d_out, int out_size, void* d_ws, size_t ws_size,
                              hipStream_t stream)
{
    const float* w   = (const float*)d_in[0];
    const float* Wh1 = (const float*)d_in[1];
    const float* bh1 = (const float*)d_in[2];
    const float* Wh2 = (const float*)d_in[3];
    const float* bh2 = (const float*)d_in[4];
    const float* Wh3 = (const float*)d_in[5];
    const float* bh3 = (const float*)d_in[6];
    const float* Wx1 = (const float*)d_in[7];
    const float* bx1 = (const float*)d_in[8];
    const float* Wx2 = (const float*)d_in[9];
    const float* bx2 = (const float*)d_in[10];
    const float* Wx3 = (const float*)d_in[11];
    const float* bx3 = (const float*)d_in[12];

    const int B = in_sizes[0] / 2;        // 65536 (divisible by 256)
    const int T = out_size / (B * 2);     // 512

    pc5_kernel<<<B / 256, 256, 0, stream>>>(
        w, Wh1, bh1, Wh2, bh2, Wh3, bh3,
        Wx1, bx1, Wx2, bx2, Wx3, bx3,
        (float2*)d_out, B, T);
}